// Round 7
// baseline (362.840 us; speedup 1.0000x reference)
//
#include <hip/hip_runtime.h>
#include <cstdint>
#include <cmath>

#define MB (1024ull * 1024ull)

typedef unsigned short u16;
typedef __attribute__((ext_vector_type(8))) short short8;
typedef __attribute__((ext_vector_type(4))) float f32x4;

enum { M_TANH = 0, M_ZRE = 1, M_QKVF = 2, M_SCALE = 3, M_PVRAW = 4, M_F32 = 5 };

__device__ __forceinline__ u16 f2b(float f) {
  union { float f; uint32_t u; } v; v.f = f;
  uint32_t r = v.u + 0x7FFFu + ((v.u >> 16) & 1u);
  return (u16)(r >> 16);
}
__device__ __forceinline__ float b2f(u16 u) {
  union { uint32_t u; float f; } v; v.u = ((uint32_t)u) << 16;
  return v.f;
}

typedef __attribute__((address_space(3))) uint32_t lds_u32;
typedef const __attribute__((address_space(1))) uint32_t glb_u32;

__device__ __forceinline__ void gload16(const void* g, void* l) {
  __builtin_amdgcn_global_load_lds((glb_u32*)g, (lds_u32*)l, 16, 0, 0);
}

// ---------------- MFMA GEMM: C = epi(A @ B^T [+ bias]) ----------------
// 128 x BNT tile, 4 waves (2x2), 3-buffer LDS, depth-2 counted-vmcnt pipeline:
//   iter t: vmcnt(LPS) [stage(t) done, stage(t+1) in flight]; s_barrier;
//           stage(t+2); ds_read(t); MFMA.  Never vmcnt(0) in steady state.
// Race invariant: barrier before stage -> all waves finished compute(t-1)
// before buf (t-1)%3 is overwritten by stage(t+2).
// LDS chunk-XOR swizzle: physical chunk p holds logical chunk p ^ ((row>>1)&3).
// M_QKVF: virtual N=4096; blocks with bn>=3072 compute f=sigmoid(A2@B2^T+bias2).
// M_PVRAW: split-K over blockIdx.z; z=0 partial -> Cf, z=1 partial -> (float*)Cb3.
template <int MODE, int BNT>
__global__ __launch_bounds__(256) void gemm(const u16* __restrict__ A,
                                            const u16* __restrict__ B,
                                            const float* __restrict__ bias,
                                            const u16* __restrict__ A2,
                                            const u16* __restrict__ B2,
                                            const float* __restrict__ bias2,
                                            u16* __restrict__ Cb,
                                            u16* __restrict__ Cb2,
                                            u16* __restrict__ Cb3,
                                            float* __restrict__ Cf,
                                            int K, int lda, int ldb, float scale) {
  constexpr int NI = 4;
  constexpr int NJ = (BNT == 128) ? 4 : 2;
  __shared__ u16 As[3][128 * 32];
  __shared__ u16 Bs[3][BNT * 32];
  const int tid = threadIdx.x;
  const int wid = tid >> 6, lane = tid & 63;

  // XCD-aware bijective block swizzle (grids per z-slice are multiples of 8)
  const int gx = gridDim.x, nwg = gx * gridDim.y;
  int id = blockIdx.y * gx + blockIdx.x;
  if ((nwg & 7) == 0) id = (id & 7) * (nwg >> 3) + (id >> 3);
  const int bm = (id / gx) * 128, bn = (id % gx) * BNT;
  const int wm = wid >> 1, wn = wid & 1;
  const int rowbase = wm * 64, colbase = wn * (BNT / 2);

  const bool isf = (MODE == M_QKVF) && (bn >= 3072);
  const u16* Ab = isf ? A2 : A;
  const u16* Bb = isf ? B2 : B;
  const int bnl = isf ? bn - 3072 : bn;
  const int kofs = (MODE == M_PVRAW) ? (int)blockIdx.z * K : 0;

  // staging: thread t -> row srow (64 rows/round), swizzled 8-elem chunk
  const int srow = tid >> 2;
  const int schunk = (tid & 3) ^ ((srow >> 1) & 3);
  const u16* gA = Ab + (size_t)(bm + srow) * lda + kofs + schunk * 8;
  const u16* gB = Bb + (size_t)(bnl + srow) * ldb + kofs + schunk * 8;

  f32x4 acc[NI][NJ];
#pragma unroll
  for (int i = 0; i < NI; ++i)
#pragma unroll
    for (int j = 0; j < NJ; ++j) acc[i][j] = (f32x4){0.f, 0.f, 0.f, 0.f};

  const int ar = lane & 15;
  const int pch = (((lane >> 4) ^ ((ar >> 1) & 3))) * 8;  // swizzled k-chunk

  const int NT = K >> 5;

  auto stage = [&](int buf, int t) {
    const u16* a = gA + (size_t)t * 32;
    const u16* b = gB + (size_t)t * 32;
    gload16(a, &As[buf][wid * 512]);
    gload16(a + (size_t)64 * lda, &As[buf][wid * 512 + 2048]);
    gload16(b, &Bs[buf][wid * 512]);
    if (BNT == 128) gload16(b + (size_t)64 * ldb, &Bs[buf][wid * 512 + 2048]);
  };

  stage(0, 0);
  stage(1, 1);
  int cb = 0;  // buffer holding tile t
  for (int t = 0; t < NT; ++t) {
    // wait for tile t's loads (ours); tile t+1's stay in flight
    if (t + 1 < NT) {
      if (BNT == 128) asm volatile("s_waitcnt vmcnt(4)" ::: "memory");
      else            asm volatile("s_waitcnt vmcnt(3)" ::: "memory");
    } else {
      asm volatile("s_waitcnt vmcnt(0)" ::: "memory");
    }
    __builtin_amdgcn_s_barrier();          // all waves' t-loads visible; compute(t-1) done everywhere
    __builtin_amdgcn_sched_barrier(0);     // pin: no LDS ops drift above the barrier
    if (t + 2 < NT) stage(cb == 0 ? 2 : cb - 1, t + 2);  // overwrite buf (t-1)%3
    short8 af[NI], bf[NJ];
#pragma unroll
    for (int i = 0; i < NI; ++i)
      af[i] = *reinterpret_cast<const short8*>(&As[cb][(rowbase + i * 16 + ar) * 32 + pch]);
#pragma unroll
    for (int j = 0; j < NJ; ++j)
      bf[j] = *reinterpret_cast<const short8*>(&Bs[cb][(colbase + j * 16 + ar) * 32 + pch]);
    __builtin_amdgcn_s_setprio(1);
#pragma unroll
    for (int i = 0; i < NI; ++i)
#pragma unroll
      for (int j = 0; j < NJ; ++j)
        acc[i][j] = __builtin_amdgcn_mfma_f32_16x16x32_bf16(af[i], bf[j], acc[i][j], 0, 0, 0);
    __builtin_amdgcn_s_setprio(0);
    cb = (cb == 2) ? 0 : cb + 1;
  }

  // split-K partial destination: z=0 -> Cf, z=1 -> (float*)Cb3 (disjoint ws regions)
  float* Cfz = Cf;
  if (MODE == M_PVRAW && blockIdx.z != 0) Cfz = (float*)Cb3;

#pragma unroll
  for (int i = 0; i < NI; ++i) {
    const int rb = bm + rowbase + i * 16 + (lane >> 4) * 4;
#pragma unroll
    for (int j = 0; j < NJ; ++j) {
      const int n = bn + colbase + j * 16 + (lane & 15);
#pragma unroll
      for (int r = 0; r < 4; ++r) {
        const int m = rb + r;
        float v = acc[i][j][r];
        if (MODE == M_TANH) {
          v = tanhf(v + bias[n]);
          Cb[(size_t)m * 2048 + n] = f2b(v);
        } else if (MODE == M_ZRE) {
          v += bias[n];
          if (n < 1024) { const float s = v / (1.f + expf(-v)); Cb[(size_t)m * 1024 + n] = f2b(s); }
          else Cb2[(size_t)m * 1024 + (n - 1024)] = f2b(v);
        } else if (MODE == M_QKVF) {
          if (isf) {
            const int nl = n - 3072;
            const float s = 1.f / (1.f + expf(-(v + bias2[nl])));
            Cb3[(size_t)m * 1024 + nl] = f2b(s);
          } else {
            v += bias[n];
            if (n < 2048) Cb[(size_t)m * 2048 + n] = f2b(v);
            else Cb2[(size_t)m * 1024 + (n - 2048)] = f2b(v);
          }
        } else if (MODE == M_SCALE) {
          Cb[(size_t)m * 4096 + n] = f2b(v * scale);
        } else if (MODE == M_PVRAW) {
          Cfz[(size_t)m * 1024 + n] = v;
        } else if (MODE == M_F32) {
          Cf[(size_t)m * 1024 + n] = v + bias[n];
        }
      }
    }
  }
}

// Zatp = f2b( (p0 + p1) * f )
__global__ __launch_bounds__(256) void pv_reduce(const float* __restrict__ p0,
                                                 const float* __restrict__ p1,
                                                 const u16* __restrict__ fvb,
                                                 u16* __restrict__ Zatp) {
  const int idx = blockIdx.x * 256 + threadIdx.x;  // 1M float4 groups
  const float4 a = reinterpret_cast<const float4*>(p0)[idx];
  const float4 b = reinterpret_cast<const float4*>(p1)[idx];
  const ushort4 f4 = reinterpret_cast<const ushort4*>(fvb)[idx];
  ushort4 o;
  o.x = f2b((a.x + b.x) * b2f(f4.x));
  o.y = f2b((a.y + b.y) * b2f(f4.y));
  o.z = f2b((a.z + b.z) * b2f(f4.z));
  o.w = f2b((a.w + b.w) * b2f(f4.w));
  reinterpret_cast<ushort4*>(Zatp)[idx] = o;
}

// ---------------- helpers ----------------
__global__ __launch_bounds__(256) void convert_all(
    const float* __restrict__ s0, const float* __restrict__ s1, const float* __restrict__ s2,
    const float* __restrict__ s3, const float* __restrict__ s4, const float* __restrict__ s5,
    const float* __restrict__ s6, const float* __restrict__ s7, const float* __restrict__ s8,
    u16* __restrict__ Wad, u16* __restrict__ Wze, u16* __restrict__ Wqkv,
    u16* __restrict__ Wfb, u16* __restrict__ Wzab) {
  const int idx = blockIdx.x * 256 + threadIdx.x;
  const float* src; u16* dst; int off;
  if      (idx < 524288)  { src = s0; dst = Wad;           off = idx; }
  else if (idx < 1048576) { src = s1; dst = Wad + 2097152; off = idx - 524288; }
  else if (idx < 1310720) { src = s2; dst = Wze;           off = idx - 1048576; }
  else if (idx < 1572864) { src = s3; dst = Wze + 1048576; off = idx - 1310720; }
  else if (idx < 1835008) { src = s4; dst = Wqkv;          off = idx - 1572864; }
  else if (idx < 2097152) { src = s5; dst = Wqkv + 1048576; off = idx - 1835008; }
  else if (idx < 2359296) { src = s6; dst = Wqkv + 2097152; off = idx - 2097152; }
  else if (idx < 2621440) { src = s7; dst = Wfb;           off = idx - 2359296; }
  else                    { src = s8; dst = Wzab;          off = idx - 2621440; }
  const float4 v = reinterpret_cast<const float4*>(src)[off];
  ushort4 o; o.x = f2b(v.x); o.y = f2b(v.y); o.z = f2b(v.z); o.w = f2b(v.w);
  reinterpret_cast<ushort4*>(dst)[off] = o;
}

__global__ void copy_bias(const float* __restrict__ ba, const float* __restrict__ bd,
                          const float* __restrict__ bz, const float* __restrict__ be,
                          const float* __restrict__ bq, const float* __restrict__ bk,
                          const float* __restrict__ bv,
                          float* __restrict__ bad, float* __restrict__ bze,
                          float* __restrict__ bqkv) {
  const int t = threadIdx.x;
  const float4* src; float4* dst;
  switch (blockIdx.x) {
    case 0: src = (const float4*)ba; dst = (float4*)bad; break;
    case 1: src = (const float4*)bd; dst = (float4*)(bad + 1024); break;
    case 2: src = (const float4*)bz; dst = (float4*)bze; break;
    case 3: src = (const float4*)be; dst = (float4*)(bze + 1024); break;
    case 4: src = (const float4*)bq; dst = (float4*)bqkv; break;
    case 5: src = (const float4*)bk; dst = (float4*)(bqkv + 1024); break;
    default: src = (const float4*)bv; dst = (float4*)(bqkv + 2048); break;
  }
  dst[t] = src[t];
}

__global__ __launch_bounds__(256) void concat_kern(const float* __restrict__ R,
                                                   u16* __restrict__ Rc) {
  const int idx = blockIdx.x * 256 + threadIdx.x;
  const int m = idx >> 9;
  const int c = (idx & 511) * 4;
  float4 v;
  if (c < 1024) {
    if (m > 0) v = *reinterpret_cast<const float4*>(&R[(size_t)(m - 1) * 1024 + c]);
    else v = make_float4(0.f, 0.f, 0.f, 0.f);
  } else {
    v = *reinterpret_cast<const float4*>(&R[(size_t)m * 1024 + (c - 1024)]);
  }
  ushort4 o; o.x = f2b(v.x); o.y = f2b(v.y); o.z = f2b(v.z); o.w = f2b(v.w);
  reinterpret_cast<ushort4*>(Rc)[idx] = o;
}

__global__ __launch_bounds__(256) void ema_combine(const float* __restrict__ R,
                                                   const u16* __restrict__ adb,
                                                   u16* __restrict__ REMA) {
  const int idx = blockIdx.x * 256 + threadIdx.x;
  const int m = idx >> 8, c4 = idx & 255;
  const float4 rt = reinterpret_cast<const float4*>(R)[idx];
  float4 rp = make_float4(0.f, 0.f, 0.f, 0.f);
  if (m > 0) rp = reinterpret_cast<const float4*>(R)[idx - 256];
  const ushort4 a4 = reinterpret_cast<const ushort4*>(adb)[m * 512 + c4];
  const ushort4 d4 = reinterpret_cast<const ushort4*>(adb)[m * 512 + 256 + c4];
  ushort4 o;
  { const float av = b2f(a4.x); o.x = f2b(av * rt.x + (1.f - av) * b2f(d4.x) * rp.x); }
  { const float av = b2f(a4.y); o.y = f2b(av * rt.y + (1.f - av) * b2f(d4.y) * rp.y); }
  { const float av = b2f(a4.z); o.z = f2b(av * rt.z + (1.f - av) * b2f(d4.z) * rp.z); }
  { const float av = b2f(a4.w); o.w = f2b(av * rt.w + (1.f - av) * b2f(d4.w) * rp.w); }
  reinterpret_cast<ushort4*>(REMA)[idx] = o;
}

__device__ __forceinline__ float waveMax(float v) {
#pragma unroll
  for (int o = 32; o; o >>= 1) v = fmaxf(v, __shfl_down(v, o));
  return v;
}
__device__ __forceinline__ float waveSum(float v) {
#pragma unroll
  for (int o = 32; o; o >>= 1) v += __shfl_down(v, o);
  return v;
}

__global__ __launch_bounds__(256) void softmax_rows(u16* __restrict__ S) {
  u16* p = S + (size_t)blockIdx.x * 4096;
  const int tid = threadIdx.x;
  float v[16];
#pragma unroll
  for (int j = 0; j < 4; ++j) {
    const ushort4 t = *reinterpret_cast<const ushort4*>(&p[tid * 4 + 1024 * j]);
    v[4 * j + 0] = b2f(t.x); v[4 * j + 1] = b2f(t.y);
    v[4 * j + 2] = b2f(t.z); v[4 * j + 3] = b2f(t.w);
  }
  float mx = -INFINITY;
#pragma unroll
  for (int j = 0; j < 16; ++j) mx = fmaxf(mx, v[j]);
  __shared__ float red[4];
  const float wm = waveMax(mx);
  if ((tid & 63) == 0) red[tid >> 6] = wm;
  __syncthreads();
  mx = fmaxf(fmaxf(red[0], red[1]), fmaxf(red[2], red[3]));
  __syncthreads();
  float sum = 0.f;
#pragma unroll
  for (int j = 0; j < 16; ++j) { v[j] = expf(v[j] - mx); sum += v[j]; }
  const float ws_ = waveSum(sum);
  if ((tid & 63) == 0) red[tid >> 6] = ws_;
  __syncthreads();
  const float inv = 1.f / (red[0] + red[1] + red[2] + red[3]);
#pragma unroll
  for (int j = 0; j < 4; ++j) {
    ushort4 t;
    t.x = f2b(v[4 * j + 0] * inv); t.y = f2b(v[4 * j + 1] * inv);
    t.z = f2b(v[4 * j + 2] * inv); t.w = f2b(v[4 * j + 3] * inv);
    *reinterpret_cast<ushort4*>(&p[tid * 4 + 1024 * j]) = t;
  }
}

__global__ __launch_bounds__(256) void transpose_b16(const u16* __restrict__ V,
                                                     u16* __restrict__ Vt) {
  __shared__ u16 t[64][72];
  const int bn = blockIdx.x * 64;
  const int bk = blockIdx.y * 64;
  const int tx = threadIdx.x & 15, ty = threadIdx.x >> 4;
#pragma unroll
  for (int i = 0; i < 64; i += 16) {
    const ushort4 v = *reinterpret_cast<const ushort4*>(&V[(size_t)(bk + ty + i) * 1024 + bn + tx * 4]);
    t[ty + i][tx * 4 + 0] = v.x; t[ty + i][tx * 4 + 1] = v.y;
    t[ty + i][tx * 4 + 2] = v.z; t[ty + i][tx * 4 + 3] = v.w;
  }
  __syncthreads();
#pragma unroll
  for (int i = 0; i < 64; i += 16) {
    ushort4 w;
    w.x = t[tx * 4 + 0][ty + i]; w.y = t[tx * 4 + 1][ty + i];
    w.z = t[tx * 4 + 2][ty + i]; w.w = t[tx * 4 + 3][ty + i];
    *reinterpret_cast<ushort4*>(&Vt[(size_t)(bn + ty + i) * 4096 + bk + tx * 4]) = w;
  }
}

// fused: i = tanh(REMA . Wi + bi); out = sigmoid( (i*tanh(REMAp+ZEMAf)+(1-i)*REMAp) . Wfin )
__global__ void final_kern(const u16* __restrict__ REMAb, const u16* __restrict__ REMApb,
                           const float* __restrict__ ZEMAf,
                           const float* __restrict__ Wi, const float* __restrict__ bi,
                           const float* __restrict__ Wfin, float* __restrict__ out) {
  const int m = blockIdx.x, l = threadIdx.x;
  float si = 0.f;
#pragma unroll
  for (int j = 0; j < 16; ++j) {
    const int n = l + 64 * j;
    si += b2f(REMAb[(size_t)m * 1024 + n]) * Wi[n];
  }
#pragma unroll
  for (int o = 32; o; o >>= 1) si += __shfl_xor(si, o);
  const float im = tanhf(si + bi[0]);
  float s = 0.f;
#pragma unroll
  for (int j = 0; j < 16; ++j) {
    const int n = l + 64 * j;
    const float rp = b2f(REMApb[(size_t)m * 1024 + n]);
    const float zf = im * tanhf(rp + ZEMAf[(size_t)m * 1024 + n]) + (1.f - im) * rp;
    s += zf * Wfin[n];
  }
#pragma unroll
  for (int o = 32; o; o >>= 1) s += __shfl_down(s, o);
  if (l == 0) out[m] = 1.f / (1.f + expf(-s));
}

extern "C" void kernel_launch(void* const* d_in, const int* in_sizes, int n_in,
                              void* d_out, int out_size, void* d_ws, size_t ws_size,
                              hipStream_t stream) {
  const float* R       = (const float*)d_in[0];
  const float* W_alpha = (const float*)d_in[1];  const float* b_alpha = (const float*)d_in[2];
  const float* W_delta = (const float*)d_in[3];  const float* b_delta = (const float*)d_in[4];
  const float* W_q     = (const float*)d_in[5];  const float* b_q     = (const float*)d_in[6];
  const float* W_k     = (const float*)d_in[7];  const float* b_k     = (const float*)d_in[8];
  const float* W_v     = (const float*)d_in[9];  const float* b_v     = (const float*)d_in[10];
  const float* W_z     = (const float*)d_in[11]; const float* b_z     = (const float*)d_in[12];
  const float* W_f     = (const float*)d_in[13]; const float* b_f     = (const float*)d_in[14];
  const float* W_EMA   = (const float*)d_in[15]; const float* b_EMA   = (const float*)d_in[16];
  const float* W_z_at  = (const float*)d_in[17]; const float* b_z_at  = (const float*)d_in[18];
  const float* W_i     = (const float*)d_in[19]; const float* b_i     = (const float*)d_in[20];
  const float* W_final = (const float*)d_in[21];
  float* out = (float*)d_out;
  uint8_t* w8 = (uint8_t*)d_ws;

  // ---- workspace layout (time-multiplexed), peak ~110 MB ----
  u16*   Rc     = (u16*)(w8 + 0 * MB);     // [0,16)  concat -> adGEMM
  u16*   Zb     = (u16*)(w8 + 0 * MB);     // [0,8)   zre -> qkvf
  u16*   Zatpb  = (u16*)(w8 + 0 * MB);     // [0,8)   pv_reduce -> zemaf
  u16*   REMApb = (u16*)(w8 + 8 * MB);     // [8,16)  zre -> final
  u16*   Wad    = (u16*)(w8 + 16 * MB);    // [16,24) conv -> adGEMM
  u16*   fvb    = (u16*)(w8 + 16 * MB);    // [16,24) qkvf -> pv_reduce
  u16*   adb    = (u16*)(w8 + 24 * MB);    // [24,40) adGEMM -> ema
  float* pvp0   = (float*)(w8 + 24 * MB);  // [24,40) PV partial 0 (adb dead)
  float* ZEMAf  = (float*)(w8 + 24 * MB);  // [24,40) zemaf -> final
  u16*   Wqkv   = (u16*)(w8 + 40 * MB);    // [40,46) conv -> qkvf
  u16*   Vtb    = (u16*)(w8 + 40 * MB);    // [40,48) transpose -> PV
  u16*   Wze    = (u16*)(w8 + 46 * MB);    // [46,50) conv -> zre
  u16*   Wfb    = (u16*)(w8 + 50 * MB);    // [50,52) conv -> qkvf(f)
  u16*   Wzab   = (u16*)(w8 + 52 * MB);    // [52,54) conv -> zemaf
  u16*   REMAb  = (u16*)(w8 + 54 * MB);    // [54,62) ema -> end
  u16*   QKb    = (u16*)(w8 + 62 * MB);    // [62,78) qkvf -> scores
  float* pvp1   = (float*)(w8 + 62 * MB);  // [62,78) PV partial 1 (QKb dead)
  u16*   Vb     = (u16*)(w8 + 78 * MB);    // [78,86) qkvf -> transpose
  u16*   Sb     = (u16*)(w8 + 78 * MB);    // [78,110) scores -> PV
  float* bad    = (float*)(w8 + 110 * MB + 64 * 1024);
  float* bze    = bad + 2048;
  float* bqkv   = bze + 2048;

  const dim3 blk(256);
  convert_all<<<11264, blk, 0, stream>>>(W_alpha, W_delta, W_z, W_EMA, W_q, W_k, W_v, W_f, W_z_at,
                                         Wad, Wze, Wqkv, Wfb, Wzab);
  concat_kern<<<8192, blk, 0, stream>>>(R, Rc);
  copy_bias<<<7, blk, 0, stream>>>(b_alpha, b_delta, b_z, b_EMA, b_q, b_k, b_v, bad, bze, bqkv);

  // alpha|delta fused: [4096][2048] = tanh(Rc @ Wad^T + bad)   (512 blocks)
  gemm<M_TANH, 128><<<dim3(16, 32), blk, 0, stream>>>(
      Rc, Wad, bad, nullptr, nullptr, nullptr, adb, nullptr, nullptr, nullptr, 2048, 2048, 2048, 1.f);
  ema_combine<<<4096, blk, 0, stream>>>(R, adb, REMAb);
  // Z | REMAp fused: N=2048 (silu -> Zb, plain -> REMApb)   (512 blocks)
  gemm<M_ZRE, 128><<<dim3(16, 32), blk, 0, stream>>>(
      REMAb, Wze, bze, nullptr, nullptr, nullptr, Zb, REMApb, nullptr, nullptr, 1024, 1024, 1024, 1.f);
  // QKV + f merged: virtual N=4096 (QK->QKb, V->Vb, f->fvb)   (1024 blocks)
  gemm<M_QKVF, 128><<<dim3(32, 32), blk, 0, stream>>>(
      Zb, Wqkv, bqkv, REMApb, Wfb, b_f, QKb, Vb, fvb, nullptr, 1024, 1024, 1024, 1.f);
  transpose_b16<<<dim3(16, 64), blk, 0, stream>>>(Vb, Vtb);
  // scores (1024 blocks, 128x128)
  gemm<M_SCALE, 128><<<dim3(32, 32), blk, 0, stream>>>(
      QKb, QKb + 1024, nullptr, nullptr, nullptr, nullptr, Sb, nullptr, nullptr, nullptr, 1024, 2048, 2048, 0.03125f);
  softmax_rows<<<4096, blk, 0, stream>>>(Sb);
  // PV split-K=2 raw partials: z=0 -> pvp0, z=1 -> pvp1 (via Cb3)   (512 blocks)
  gemm<M_PVRAW, 128><<<dim3(8, 32, 2), blk, 0, stream>>>(
      Sb, Vtb, nullptr, nullptr, nullptr, nullptr, nullptr, nullptr, (u16*)pvp1, pvp0, 2048, 4096, 4096, 1.f);
  // Zatp = f * (p0 + p1)
  pv_reduce<<<4096, blk, 0, stream>>>(pvp0, pvp1, fvb, Zatpb);
  // Z_EMA_f (f32)   (512 blocks, 128x64)
  gemm<M_F32, 64><<<dim3(16, 32), blk, 0, stream>>>(
      Zatpb, Wzab, b_z_at, nullptr, nullptr, nullptr, nullptr, nullptr, nullptr, ZEMAf, 1024, 1024, 1024, 1.f);
  // fused i + final
  final_kern<<<4096, 64, 0, stream>>>(REMAb, REMApb, ZEMAf, W_i, b_i, W_final, out);
}

// Round 8
// 351.590 us; speedup vs baseline: 1.0320x; 1.0320x over previous
//
#include <hip/hip_runtime.h>
#include <cstdint>
#include <cmath>

#define MB (1024ull * 1024ull)

typedef unsigned short u16;
typedef __attribute__((ext_vector_type(8))) short short8;
typedef __attribute__((ext_vector_type(4))) float f32x4;

enum { M_TANH = 0, M_ZRE = 1, M_QKVF = 2, M_SCALE = 3, M_PVRAW = 4, M_F32 = 5 };

__device__ __forceinline__ u16 f2b(float f) {
  union { float f; uint32_t u; } v; v.f = f;
  uint32_t r = v.u + 0x7FFFu + ((v.u >> 16) & 1u);
  return (u16)(r >> 16);
}
__device__ __forceinline__ float b2f(u16 u) {
  union { uint32_t u; float f; } v; v.u = ((uint32_t)u) << 16;
  return v.f;
}

typedef __attribute__((address_space(3))) uint32_t lds_u32;
typedef const __attribute__((address_space(1))) uint32_t glb_u32;

__device__ __forceinline__ void gload16(const void* g, void* l) {
  __builtin_amdgcn_global_load_lds((glb_u32*)g, (lds_u32*)l, 16, 0, 0);
}

// ---------------- MFMA GEMM: C = epi(A @ B^T [+ bias]) ----------------
// 64 x 128 tile, 4 waves (1x4, each 64 rows x 32 cols), 3-buffer LDS (36 KB),
// depth-2 counted-vmcnt pipeline:
//   iter t: s_waitcnt vmcnt(3)  [stage(t) landed; stage(t+1)'s 3 loads in flight]
//           s_barrier            [all waves' t-loads visible; compute(t-1) done]
//           stage(t+2) -> buf (cb+2)%3   [overwrites buf of tile t-1]
//           ds_read(t); MFMA x8.         Never vmcnt(0) until the tail.
// LDS chunk-XOR swizzle: physical chunk p holds logical chunk p ^ ((row>>1)&3).
// M_QKVF: virtual N=4096; blocks with bn>=3072 compute f=sigmoid(A2@B2^T+bias2).
// M_PVRAW: split-K over blockIdx.z; z=0 partial -> Cf, z=1 partial -> (float*)Cb3.
template <int MODE>
__global__ __launch_bounds__(256) void gemm(const u16* __restrict__ A,
                                            const u16* __restrict__ B,
                                            const float* __restrict__ bias,
                                            const u16* __restrict__ A2,
                                            const u16* __restrict__ B2,
                                            const float* __restrict__ bias2,
                                            u16* __restrict__ Cb,
                                            u16* __restrict__ Cb2,
                                            u16* __restrict__ Cb3,
                                            float* __restrict__ Cf,
                                            int K, int lda, int ldb, float scale) {
  constexpr int NI = 4;
  constexpr int NJ = 2;
  __shared__ u16 As[3][64 * 32];
  __shared__ u16 Bs[3][128 * 32];
  const int tid = threadIdx.x;
  const int wid = tid >> 6, lane = tid & 63;

  // XCD-aware bijective block swizzle (grids per z-slice are multiples of 8)
  const int gx = gridDim.x, nwg = gx * gridDim.y;
  int id = blockIdx.y * gx + blockIdx.x;
  if ((nwg & 7) == 0) id = (id & 7) * (nwg >> 3) + (id >> 3);
  const int bm = (id / gx) * 64, bn = (id % gx) * 128;
  const int colbase = wid * 32;

  const bool isf = (MODE == M_QKVF) && (bn >= 3072);
  const u16* Ab = isf ? A2 : A;
  const u16* Bb = isf ? B2 : B;
  const int bnl = isf ? bn - 3072 : bn;
  const int kofs = (MODE == M_PVRAW) ? (int)blockIdx.z * K : 0;

  // staging: thread t -> row srow (64 rows/round), swizzled 8-elem chunk
  const int srow = tid >> 2;
  const int schunk = (tid & 3) ^ ((srow >> 1) & 3);
  const u16* gA = Ab + (size_t)(bm + srow) * lda + kofs + schunk * 8;
  const u16* gB = Bb + (size_t)(bnl + srow) * ldb + kofs + schunk * 8;

  f32x4 acc[NI][NJ];
#pragma unroll
  for (int i = 0; i < NI; ++i)
#pragma unroll
    for (int j = 0; j < NJ; ++j) acc[i][j] = (f32x4){0.f, 0.f, 0.f, 0.f};

  const int ar = lane & 15;
  const int pch = (((lane >> 4) ^ ((ar >> 1) & 3))) * 8;  // swizzled k-chunk

  const int NT = K >> 5;

  auto stage = [&](int buf, int t) {
    const u16* a = gA + (size_t)t * 32;
    const u16* b = gB + (size_t)t * 32;
    gload16(a, &As[buf][wid * 512]);
    gload16(b, &Bs[buf][wid * 512]);
    gload16(b + (size_t)64 * ldb, &Bs[buf][wid * 512 + 2048]);
  };

  stage(0, 0);
  stage(1, 1);
  int cb = 0;  // buffer holding tile t
  for (int t = 0; t < NT; ++t) {
    // wait for tile t's 3 loads; tile t+1's 3 stay in flight
    if (t + 1 < NT) asm volatile("s_waitcnt vmcnt(3)" ::: "memory");
    else            asm volatile("s_waitcnt vmcnt(0)" ::: "memory");
    __builtin_amdgcn_s_barrier();  // all waves' t-loads visible; compute(t-1) done everywhere
    if (t + 2 < NT) stage((cb + 2) % 3, t + 2);  // overwrite buf of tile t-1
    short8 af[NI], bf[NJ];
#pragma unroll
    for (int i = 0; i < NI; ++i)
      af[i] = *reinterpret_cast<const short8*>(&As[cb][(i * 16 + ar) * 32 + pch]);
#pragma unroll
    for (int j = 0; j < NJ; ++j)
      bf[j] = *reinterpret_cast<const short8*>(&Bs[cb][(colbase + j * 16 + ar) * 32 + pch]);
    __builtin_amdgcn_s_setprio(1);
#pragma unroll
    for (int i = 0; i < NI; ++i)
#pragma unroll
      for (int j = 0; j < NJ; ++j)
        acc[i][j] = __builtin_amdgcn_mfma_f32_16x16x32_bf16(af[i], bf[j], acc[i][j], 0, 0, 0);
    __builtin_amdgcn_s_setprio(0);
    cb = (cb == 2) ? 0 : cb + 1;
  }

  // split-K partial destination: z=0 -> Cf, z=1 -> (float*)Cb3 (disjoint ws regions)
  float* Cfz = Cf;
  if (MODE == M_PVRAW && blockIdx.z != 0) Cfz = (float*)Cb3;

#pragma unroll
  for (int i = 0; i < NI; ++i) {
    const int rb = bm + i * 16 + (lane >> 4) * 4;
#pragma unroll
    for (int j = 0; j < NJ; ++j) {
      const int n = bn + colbase + j * 16 + (lane & 15);
#pragma unroll
      for (int r = 0; r < 4; ++r) {
        const int m = rb + r;
        float v = acc[i][j][r];
        if (MODE == M_TANH) {
          v = tanhf(v + bias[n]);
          Cb[(size_t)m * 2048 + n] = f2b(v);
        } else if (MODE == M_ZRE) {
          v += bias[n];
          if (n < 1024) { const float s = v / (1.f + expf(-v)); Cb[(size_t)m * 1024 + n] = f2b(s); }
          else Cb2[(size_t)m * 1024 + (n - 1024)] = f2b(v);
        } else if (MODE == M_QKVF) {
          if (isf) {
            const int nl = n - 3072;
            const float s = 1.f / (1.f + expf(-(v + bias2[nl])));
            Cb3[(size_t)m * 1024 + nl] = f2b(s);
          } else {
            v += bias[n];
            if (n < 2048) Cb[(size_t)m * 2048 + n] = f2b(v);
            else Cb2[(size_t)m * 1024 + (n - 2048)] = f2b(v);
          }
        } else if (MODE == M_SCALE) {
          Cb[(size_t)m * 4096 + n] = f2b(v * scale);
        } else if (MODE == M_PVRAW) {
          Cfz[(size_t)m * 1024 + n] = v;
        } else if (MODE == M_F32) {
          Cf[(size_t)m * 1024 + n] = v + bias[n];
        }
      }
    }
  }
}

// Zatp = f2b( (p0 + p1) * f )
__global__ __launch_bounds__(256) void pv_reduce(const float* __restrict__ p0,
                                                 const float* __restrict__ p1,
                                                 const u16* __restrict__ fvb,
                                                 u16* __restrict__ Zatp) {
  const int idx = blockIdx.x * 256 + threadIdx.x;  // 1M float4 groups
  const float4 a = reinterpret_cast<const float4*>(p0)[idx];
  const float4 b = reinterpret_cast<const float4*>(p1)[idx];
  const ushort4 f4 = reinterpret_cast<const ushort4*>(fvb)[idx];
  ushort4 o;
  o.x = f2b((a.x + b.x) * b2f(f4.x));
  o.y = f2b((a.y + b.y) * b2f(f4.y));
  o.z = f2b((a.z + b.z) * b2f(f4.z));
  o.w = f2b((a.w + b.w) * b2f(f4.w));
  reinterpret_cast<ushort4*>(Zatp)[idx] = o;
}

// ---------------- helpers ----------------
__global__ __launch_bounds__(256) void convert_all(
    const float* __restrict__ s0, const float* __restrict__ s1, const float* __restrict__ s2,
    const float* __restrict__ s3, const float* __restrict__ s4, const float* __restrict__ s5,
    const float* __restrict__ s6, const float* __restrict__ s7, const float* __restrict__ s8,
    u16* __restrict__ Wad, u16* __restrict__ Wze, u16* __restrict__ Wqkv,
    u16* __restrict__ Wfb, u16* __restrict__ Wzab) {
  const int idx = blockIdx.x * 256 + threadIdx.x;
  const float* src; u16* dst; int off;
  if      (idx < 524288)  { src = s0; dst = Wad;           off = idx; }
  else if (idx < 1048576) { src = s1; dst = Wad + 2097152; off = idx - 524288; }
  else if (idx < 1310720) { src = s2; dst = Wze;           off = idx - 1048576; }
  else if (idx < 1572864) { src = s3; dst = Wze + 1048576; off = idx - 1310720; }
  else if (idx < 1835008) { src = s4; dst = Wqkv;          off = idx - 1572864; }
  else if (idx < 2097152) { src = s5; dst = Wqkv + 1048576; off = idx - 1835008; }
  else if (idx < 2359296) { src = s6; dst = Wqkv + 2097152; off = idx - 2097152; }
  else if (idx < 2621440) { src = s7; dst = Wfb;           off = idx - 2359296; }
  else                    { src = s8; dst = Wzab;          off = idx - 2621440; }
  const float4 v = reinterpret_cast<const float4*>(src)[off];
  ushort4 o; o.x = f2b(v.x); o.y = f2b(v.y); o.z = f2b(v.z); o.w = f2b(v.w);
  reinterpret_cast<ushort4*>(dst)[off] = o;
}

__global__ void copy_bias(const float* __restrict__ ba, const float* __restrict__ bd,
                          const float* __restrict__ bz, const float* __restrict__ be,
                          const float* __restrict__ bq, const float* __restrict__ bk,
                          const float* __restrict__ bv,
                          float* __restrict__ bad, float* __restrict__ bze,
                          float* __restrict__ bqkv) {
  const int t = threadIdx.x;
  const float4* src; float4* dst;
  switch (blockIdx.x) {
    case 0: src = (const float4*)ba; dst = (float4*)bad; break;
    case 1: src = (const float4*)bd; dst = (float4*)(bad + 1024); break;
    case 2: src = (const float4*)bz; dst = (float4*)bze; break;
    case 3: src = (const float4*)be; dst = (float4*)(bze + 1024); break;
    case 4: src = (const float4*)bq; dst = (float4*)bqkv; break;
    case 5: src = (const float4*)bk; dst = (float4*)(bqkv + 1024); break;
    default: src = (const float4*)bv; dst = (float4*)(bqkv + 2048); break;
  }
  dst[t] = src[t];
}

__global__ __launch_bounds__(256) void concat_kern(const float* __restrict__ R,
                                                   u16* __restrict__ Rc) {
  const int idx = blockIdx.x * 256 + threadIdx.x;
  const int m = idx >> 9;
  const int c = (idx & 511) * 4;
  float4 v;
  if (c < 1024) {
    if (m > 0) v = *reinterpret_cast<const float4*>(&R[(size_t)(m - 1) * 1024 + c]);
    else v = make_float4(0.f, 0.f, 0.f, 0.f);
  } else {
    v = *reinterpret_cast<const float4*>(&R[(size_t)m * 1024 + (c - 1024)]);
  }
  ushort4 o; o.x = f2b(v.x); o.y = f2b(v.y); o.z = f2b(v.z); o.w = f2b(v.w);
  reinterpret_cast<ushort4*>(Rc)[idx] = o;
}

__global__ __launch_bounds__(256) void ema_combine(const float* __restrict__ R,
                                                   const u16* __restrict__ adb,
                                                   u16* __restrict__ REMA) {
  const int idx = blockIdx.x * 256 + threadIdx.x;
  const int m = idx >> 8, c4 = idx & 255;
  const float4 rt = reinterpret_cast<const float4*>(R)[idx];
  float4 rp = make_float4(0.f, 0.f, 0.f, 0.f);
  if (m > 0) rp = reinterpret_cast<const float4*>(R)[idx - 256];
  const ushort4 a4 = reinterpret_cast<const ushort4*>(adb)[m * 512 + c4];
  const ushort4 d4 = reinterpret_cast<const ushort4*>(adb)[m * 512 + 256 + c4];
  ushort4 o;
  { const float av = b2f(a4.x); o.x = f2b(av * rt.x + (1.f - av) * b2f(d4.x) * rp.x); }
  { const float av = b2f(a4.y); o.y = f2b(av * rt.y + (1.f - av) * b2f(d4.y) * rp.y); }
  { const float av = b2f(a4.z); o.z = f2b(av * rt.z + (1.f - av) * b2f(d4.z) * rp.z); }
  { const float av = b2f(a4.w); o.w = f2b(av * rt.w + (1.f - av) * b2f(d4.w) * rp.w); }
  reinterpret_cast<ushort4*>(REMA)[idx] = o;
}

__device__ __forceinline__ float waveMax(float v) {
#pragma unroll
  for (int o = 32; o; o >>= 1) v = fmaxf(v, __shfl_down(v, o));
  return v;
}
__device__ __forceinline__ float waveSum(float v) {
#pragma unroll
  for (int o = 32; o; o >>= 1) v += __shfl_down(v, o);
  return v;
}

__global__ __launch_bounds__(256) void softmax_rows(u16* __restrict__ S) {
  u16* p = S + (size_t)blockIdx.x * 4096;
  const int tid = threadIdx.x;
  float v[16];
#pragma unroll
  for (int j = 0; j < 4; ++j) {
    const ushort4 t = *reinterpret_cast<const ushort4*>(&p[tid * 4 + 1024 * j]);
    v[4 * j + 0] = b2f(t.x); v[4 * j + 1] = b2f(t.y);
    v[4 * j + 2] = b2f(t.z); v[4 * j + 3] = b2f(t.w);
  }
  float mx = -INFINITY;
#pragma unroll
  for (int j = 0; j < 16; ++j) mx = fmaxf(mx, v[j]);
  __shared__ float red[4];
  const float wm = waveMax(mx);
  if ((tid & 63) == 0) red[tid >> 6] = wm;
  __syncthreads();
  mx = fmaxf(fmaxf(red[0], red[1]), fmaxf(red[2], red[3]));
  __syncthreads();
  float sum = 0.f;
#pragma unroll
  for (int j = 0; j < 16; ++j) { v[j] = expf(v[j] - mx); sum += v[j]; }
  const float ws_ = waveSum(sum);
  if ((tid & 63) == 0) red[tid >> 6] = ws_;
  __syncthreads();
  const float inv = 1.f / (red[0] + red[1] + red[2] + red[3]);
#pragma unroll
  for (int j = 0; j < 4; ++j) {
    ushort4 t;
    t.x = f2b(v[4 * j + 0] * inv); t.y = f2b(v[4 * j + 1] * inv);
    t.z = f2b(v[4 * j + 2] * inv); t.w = f2b(v[4 * j + 3] * inv);
    *reinterpret_cast<ushort4*>(&p[tid * 4 + 1024 * j]) = t;
  }
}

__global__ __launch_bounds__(256) void transpose_b16(const u16* __restrict__ V,
                                                     u16* __restrict__ Vt) {
  __shared__ u16 t[64][72];
  const int bn = blockIdx.x * 64;
  const int bk = blockIdx.y * 64;
  const int tx = threadIdx.x & 15, ty = threadIdx.x >> 4;
#pragma unroll
  for (int i = 0; i < 64; i += 16) {
    const ushort4 v = *reinterpret_cast<const ushort4*>(&V[(size_t)(bk + ty + i) * 1024 + bn + tx * 4]);
    t[ty + i][tx * 4 + 0] = v.x; t[ty + i][tx * 4 + 1] = v.y;
    t[ty + i][tx * 4 + 2] = v.z; t[ty + i][tx * 4 + 3] = v.w;
  }
  __syncthreads();
#pragma unroll
  for (int i = 0; i < 64; i += 16) {
    ushort4 w;
    w.x = t[tx * 4 + 0][ty + i]; w.y = t[tx * 4 + 1][ty + i];
    w.z = t[tx * 4 + 2][ty + i]; w.w = t[tx * 4 + 3][ty + i];
    *reinterpret_cast<ushort4*>(&Vt[(size_t)(bn + ty + i) * 4096 + bk + tx * 4]) = w;
  }
}

// fused: i = tanh(REMA . Wi + bi); out = sigmoid( (i*tanh(REMAp+ZEMAf)+(1-i)*REMAp) . Wfin )
__global__ void final_kern(const u16* __restrict__ REMAb, const u16* __restrict__ REMApb,
                           const float* __restrict__ ZEMAf,
                           const float* __restrict__ Wi, const float* __restrict__ bi,
                           const float* __restrict__ Wfin, float* __restrict__ out) {
  const int m = blockIdx.x, l = threadIdx.x;
  float si = 0.f;
#pragma unroll
  for (int j = 0; j < 16; ++j) {
    const int n = l + 64 * j;
    si += b2f(REMAb[(size_t)m * 1024 + n]) * Wi[n];
  }
#pragma unroll
  for (int o = 32; o; o >>= 1) si += __shfl_xor(si, o);
  const float im = tanhf(si + bi[0]);
  float s = 0.f;
#pragma unroll
  for (int j = 0; j < 16; ++j) {
    const int n = l + 64 * j;
    const float rp = b2f(REMApb[(size_t)m * 1024 + n]);
    const float zf = im * tanhf(rp + ZEMAf[(size_t)m * 1024 + n]) + (1.f - im) * rp;
    s += zf * Wfin[n];
  }
#pragma unroll
  for (int o = 32; o; o >>= 1) s += __shfl_down(s, o);
  if (l == 0) out[m] = 1.f / (1.f + expf(-s));
}

extern "C" void kernel_launch(void* const* d_in, const int* in_sizes, int n_in,
                              void* d_out, int out_size, void* d_ws, size_t ws_size,
                              hipStream_t stream) {
  const float* R       = (const float*)d_in[0];
  const float* W_alpha = (const float*)d_in[1];  const float* b_alpha = (const float*)d_in[2];
  const float* W_delta = (const float*)d_in[3];  const float* b_delta = (const float*)d_in[4];
  const float* W_q     = (const float*)d_in[5];  const float* b_q     = (const float*)d_in[6];
  const float* W_k     = (const float*)d_in[7];  const float* b_k     = (const float*)d_in[8];
  const float* W_v     = (const float*)d_in[9];  const float* b_v     = (const float*)d_in[10];
  const float* W_z     = (const float*)d_in[11]; const float* b_z     = (const float*)d_in[12];
  const float* W_f     = (const float*)d_in[13]; const float* b_f     = (const float*)d_in[14];
  const float* W_EMA   = (const float*)d_in[15]; const float* b_EMA   = (const float*)d_in[16];
  const float* W_z_at  = (const float*)d_in[17]; const float* b_z_at  = (const float*)d_in[18];
  const float* W_i     = (const float*)d_in[19]; const float* b_i     = (const float*)d_in[20];
  const float* W_final = (const float*)d_in[21];
  float* out = (float*)d_out;
  uint8_t* w8 = (uint8_t*)d_ws;

  // ---- workspace layout (time-multiplexed), peak ~110 MB ----
  u16*   Rc     = (u16*)(w8 + 0 * MB);     // [0,16)  concat -> adGEMM
  u16*   Zb     = (u16*)(w8 + 0 * MB);     // [0,8)   zre -> qkvf
  u16*   Zatpb  = (u16*)(w8 + 0 * MB);     // [0,8)   pv_reduce -> zemaf
  u16*   REMApb = (u16*)(w8 + 8 * MB);     // [8,16)  zre -> final
  u16*   Wad    = (u16*)(w8 + 16 * MB);    // [16,24) conv -> adGEMM
  u16*   fvb    = (u16*)(w8 + 16 * MB);    // [16,24) qkvf -> pv_reduce
  u16*   adb    = (u16*)(w8 + 24 * MB);    // [24,40) adGEMM -> ema
  float* pvp0   = (float*)(w8 + 24 * MB);  // [24,40) PV partial 0 (adb dead)
  float* ZEMAf  = (float*)(w8 + 24 * MB);  // [24,40) zemaf -> final
  u16*   Wqkv   = (u16*)(w8 + 40 * MB);    // [40,46) conv -> qkvf
  u16*   Vtb    = (u16*)(w8 + 40 * MB);    // [40,48) transpose -> PV
  u16*   Wze    = (u16*)(w8 + 46 * MB);    // [46,50) conv -> zre
  u16*   Wfb    = (u16*)(w8 + 50 * MB);    // [50,52) conv -> qkvf(f)
  u16*   Wzab   = (u16*)(w8 + 52 * MB);    // [52,54) conv -> zemaf
  u16*   REMAb  = (u16*)(w8 + 54 * MB);    // [54,62) ema -> end
  u16*   QKb    = (u16*)(w8 + 62 * MB);    // [62,78) qkvf -> scores
  float* pvp1   = (float*)(w8 + 62 * MB);  // [62,78) PV partial 1 (QKb dead)
  u16*   Vb     = (u16*)(w8 + 78 * MB);    // [78,86) qkvf -> transpose
  u16*   Sb     = (u16*)(w8 + 78 * MB);    // [78,110) scores -> PV
  float* bad    = (float*)(w8 + 110 * MB + 64 * 1024);
  float* bze    = bad + 2048;
  float* bqkv   = bze + 2048;

  const dim3 blk(256);
  convert_all<<<11264, blk, 0, stream>>>(W_alpha, W_delta, W_z, W_EMA, W_q, W_k, W_v, W_f, W_z_at,
                                         Wad, Wze, Wqkv, Wfb, Wzab);
  concat_kern<<<8192, blk, 0, stream>>>(R, Rc);
  copy_bias<<<7, blk, 0, stream>>>(b_alpha, b_delta, b_z, b_EMA, b_q, b_k, b_v, bad, bze, bqkv);

  // alpha|delta fused: [4096][2048] = tanh(Rc @ Wad^T + bad)   (1024 blocks)
  gemm<M_TANH><<<dim3(16, 64), blk, 0, stream>>>(
      Rc, Wad, bad, nullptr, nullptr, nullptr, adb, nullptr, nullptr, nullptr, 2048, 2048, 2048, 1.f);
  ema_combine<<<4096, blk, 0, stream>>>(R, adb, REMAb);
  // Z | REMAp fused: N=2048 (silu -> Zb, plain -> REMApb)   (1024 blocks)
  gemm<M_ZRE><<<dim3(16, 64), blk, 0, stream>>>(
      REMAb, Wze, bze, nullptr, nullptr, nullptr, Zb, REMApb, nullptr, nullptr, 1024, 1024, 1024, 1.f);
  // QKV + f merged: virtual N=4096 (QK->QKb, V->Vb, f->fvb)   (2048 blocks)
  gemm<M_QKVF><<<dim3(32, 64), blk, 0, stream>>>(
      Zb, Wqkv, bqkv, REMApb, Wfb, b_f, QKb, Vb, fvb, nullptr, 1024, 1024, 1024, 1.f);
  transpose_b16<<<dim3(16, 64), blk, 0, stream>>>(Vb, Vtb);
  // scores (2048 blocks, 64x128)
  gemm<M_SCALE><<<dim3(32, 64), blk, 0, stream>>>(
      QKb, QKb + 1024, nullptr, nullptr, nullptr, nullptr, Sb, nullptr, nullptr, nullptr, 1024, 2048, 2048, 0.03125f);
  softmax_rows<<<4096, blk, 0, stream>>>(Sb);
  // PV split-K=2 raw partials: z=0 -> pvp0, z=1 -> pvp1 (via Cb3)   (1024 blocks)
  gemm<M_PVRAW><<<dim3(8, 64, 2), blk, 0, stream>>>(
      Sb, Vtb, nullptr, nullptr, nullptr, nullptr, nullptr, nullptr, (u16*)pvp1, pvp0, 2048, 4096, 4096, 1.f);
  // Zatp = f * (p0 + p1)
  pv_reduce<<<4096, blk, 0, stream>>>(pvp0, pvp1, fvb, Zatpb);
  // Z_EMA_f (f32)   (512 blocks)
  gemm<M_F32><<<dim3(8, 64), blk, 0, stream>>>(
      Zatpb, Wzab, b_z_at, nullptr, nullptr, nullptr, nullptr, nullptr, nullptr, ZEMAf, 1024, 1024, 1024, 1.f);
  // fused i + final
  final_kern<<<4096, 64, 0, stream>>>(REMAb, REMApb, ZEMAf, W_i, b_i, W_final, out);
}